// Round 6
// baseline (191.386 us; speedup 1.0000x reference)
//
#include <hip/hip_runtime.h>

// VQ-VAE eval forward, MFMA bf16x3-split, R6:
//  - Root cause R2-R5: only 2048 waves = 2 waves/SIMD -> latency-bound.
//  - K-split 2-way: 1024 blocks (128 queries x 512 codes) = 4096 waves = 4/SIMD.
//    Cross-block argmin via packed (monotone-dist<<32|idx) u64 atomicMin in ws.
//  - B-fragments read directly from L2-resident precomputed planes (no LDS).
//  - vq_post: winners -> indices/flags/gather/loss/usage (last-block finalize).

#define DIMS 64
#define K_CODES 1024
#define NQ 65536
#define HW 1024
#define TOT 4194304
#define PLANE 4096                 // shorts per plane per 64-code tile

// ws layout (bytes)
#define WS_NORM   0        // float[1024]
#define WS_FLAGS  4096     // int[1024]
#define WS_LOSS   8192     // float
#define WS_CNT    8256     // int
#define WS_PLANES 16384    // ushort[16 tiles][3 planes][8 octets][64 codes][8] (384 KB)
#define WS_PACK   409600   // u64[65536] (512 KB)

typedef __attribute__((ext_vector_type(8))) short v8s;
typedef __attribute__((ext_vector_type(4))) float f32x4;
typedef unsigned long long u64;

__device__ inline unsigned short f2bf(float x) {
    union { float f; unsigned u; } v; v.f = x;
    unsigned r = v.u + 0x7fff + ((v.u >> 16) & 1);  // RNE
    return (unsigned short)(r >> 16);
}
__device__ inline float bf2f(unsigned short h) {
    union { unsigned u; float f; } v; v.u = ((unsigned)h) << 16; return v.f;
}
__device__ inline unsigned fenc(float d) {  // monotone float->uint
    union { float f; unsigned u; } v; v.f = d;
    return (v.u & 0x80000000u) ? ~v.u : (v.u | 0x80000000u);
}

#define MFMA16(A_, B_, C_) __builtin_amdgcn_mfma_f32_16x16x32_bf16(A_, B_, C_, 0, 0, 0)

// ---------------- Kernel A: split planes + norms + init (64 blocks x 256) ----------------
__global__ void vq_prep(const float* __restrict__ emb, char* __restrict__ ws) {
    float* norms = (float*)(ws + WS_NORM);
    int*   flags = (int*)(ws + WS_FLAGS);
    unsigned short* planes = (unsigned short*)(ws + WS_PLANES);
    u64* pack = (u64*)(ws + WS_PACK);

    const int tid = threadIdx.x;
    const int gt  = blockIdx.x * 256 + tid;  // 0..16383

    {   // one float4 of emb per thread -> 3 plane entries
        int f4 = gt;
        int code = f4 >> 4;
        int t    = code >> 6;
        int c    = code & 63;
        int o    = (f4 >> 1) & 7;
        int sub  = (f4 & 1) * 4;
        float4 v = ((const float4*)emb)[f4];
        float xs[4] = {v.x, v.y, v.z, v.w};
        unsigned short h[4], m[4], l[4];
#pragma unroll
        for (int q = 0; q < 4; ++q) {
            float x = xs[q];
            unsigned short hh = f2bf(x);  float r1 = x - bf2f(hh);
            unsigned short mh = f2bf(r1); float r2 = r1 - bf2f(mh);
            h[q] = hh; m[q] = mh; l[q] = f2bf(r2);
        }
        unsigned short* base = planes + (size_t)t * 12288 + ((o * 64 + c) * 8 + sub);
        uint2 uh, um, ul;
        uh.x = (unsigned)h[0] | ((unsigned)h[1] << 16);
        uh.y = (unsigned)h[2] | ((unsigned)h[3] << 16);
        um.x = (unsigned)m[0] | ((unsigned)m[1] << 16);
        um.y = (unsigned)m[2] | ((unsigned)m[3] << 16);
        ul.x = (unsigned)l[0] | ((unsigned)l[1] << 16);
        ul.y = (unsigned)l[2] | ((unsigned)l[3] << 16);
        *(uint2*)(base)             = uh;
        *(uint2*)(base + PLANE)     = um;
        *(uint2*)(base + 2 * PLANE) = ul;
    }
    // pack init: 4 u64 per thread
#pragma unroll
    for (int i = 0; i < 4; ++i) pack[gt * 4 + i] = ~0ull;
    // norms + flags
    if (gt < K_CODES) {
        const float4* row = (const float4*)(emb + gt * DIMS);
        float s = 0.f;
#pragma unroll
        for (int i = 0; i < 16; ++i) {
            float4 v = row[i];
            s += v.x * v.x + v.y * v.y + v.z * v.z + v.w * v.w;
        }
        norms[gt] = s;
        flags[gt] = 0;
    }
    if (gt == 0) { *(float*)(ws + WS_LOSS) = 0.f; *(int*)(ws + WS_CNT) = 0; }
}

// ---------------- Kernel B: MFMA distances + packed argmin (1024 blocks x 256) --------
// Block: 128 queries x 512 codes (khalf = blockIdx&1). Wave: 32 queries, 8 tiles.
__global__ __launch_bounds__(256, 4)
void vq_main(const float* __restrict__ z_e, char* __restrict__ ws) {
    const float* norms = (const float*)(ws + WS_NORM);
    u64* pack = (u64*)(ws + WS_PACK);

    const int tid  = threadIdx.x;
    const int lane = tid & 63;
    const int wid  = tid >> 6;
    const int khalf = blockIdx.x & 1;
    const int qbase = (blockIdx.x >> 1) * 128;
    const int b    = qbase >> 10;
    const int hwb  = qbase & (HW - 1);
    const int col  = lane & 15;
    const int qd   = lane >> 4;

    // Per-lane base into frag-ready planes (v8s = 16 B units).
    const v8s* Pl = ((const v8s*)(ws + WS_PLANES)) + qd * 64 + col;

    // ---- A fragments: split queries into 3 bf16 planes ----
    v8s afr[2][2][3];
    {
        const float* zb = z_e + b * (DIMS * HW);
#pragma unroll
        for (int rt = 0; rt < 2; ++rt) {
            int hwq = hwb + wid * 32 + rt * 16 + col;
#pragma unroll
            for (int kc = 0; kc < 2; ++kc) {
                int dbase = kc * 32 + qd * 8;
#pragma unroll
                for (int j = 0; j < 8; ++j) {
                    float x = zb[(dbase + j) * HW + hwq];
                    unsigned short h = f2bf(x);  float r1 = x - bf2f(h);
                    unsigned short m = f2bf(r1); float r2 = r1 - bf2f(m);
                    afr[rt][kc][0][j] = (short)h;
                    afr[rt][kc][1][j] = (short)m;
                    afr[rt][kc][2][j] = (short)f2bf(r2);
                }
            }
        }
    }

    float bestv[2][4];
    int   besti[2][4];
#pragma unroll
    for (int rt = 0; rt < 2; ++rt)
#pragma unroll
        for (int r = 0; r < 4; ++r) { bestv[rt][r] = 3.4e38f; besti[rt][r] = 0; }

    for (int tt = 0; tt < 8; ++tt) {
        const int t = khalf * 8 + tt;
        const v8s* Pt = Pl + t * 1536;
#pragma unroll
        for (int cs = 0; cs < 4; ++cs) {
            float nrm = norms[t * 64 + cs * 16 + col];
            v8s bfr[2][3];
#pragma unroll
            for (int kc = 0; kc < 2; ++kc)
#pragma unroll
                for (int p = 0; p < 3; ++p)
                    bfr[kc][p] = Pt[p * 512 + kc * 256 + cs * 16];
            f32x4 acc0 = {0.f, 0.f, 0.f, 0.f};
            f32x4 acc1 = {0.f, 0.f, 0.f, 0.f};
#pragma unroll
            for (int kc = 0; kc < 2; ++kc) {
                acc0 = MFMA16(afr[0][kc][0], bfr[kc][0], acc0);  // hh
                acc1 = MFMA16(afr[1][kc][0], bfr[kc][0], acc1);
                acc0 = MFMA16(afr[0][kc][0], bfr[kc][1], acc0);  // hm
                acc1 = MFMA16(afr[1][kc][0], bfr[kc][1], acc1);
                acc0 = MFMA16(afr[0][kc][1], bfr[kc][0], acc0);  // mh
                acc1 = MFMA16(afr[1][kc][1], bfr[kc][0], acc1);
                acc0 = MFMA16(afr[0][kc][1], bfr[kc][1], acc0);  // mm
                acc1 = MFMA16(afr[1][kc][1], bfr[kc][1], acc1);
                acc0 = MFMA16(afr[0][kc][0], bfr[kc][2], acc0);  // hl
                acc1 = MFMA16(afr[1][kc][0], bfr[kc][2], acc1);
                acc0 = MFMA16(afr[0][kc][2], bfr[kc][0], acc0);  // lh
                acc1 = MFMA16(afr[1][kc][2], bfr[kc][0], acc1);
            }
            int cbase = t * 64 + cs * 16 + col;
#pragma unroll
            for (int r = 0; r < 4; ++r) {
                float d0 = fmaf(-2.f, acc0[r], nrm);
                if (d0 < bestv[0][r]) { bestv[0][r] = d0; besti[0][r] = cbase; }
                float d1 = fmaf(-2.f, acc1[r], nrm);
                if (d1 < bestv[1][r]) { bestv[1][r] = d1; besti[1][r] = cbase; }
            }
        }
    }

    // ---- argmin across 16 columns (C/D: row=qd*4+r, col=lane&15), then global combine
#pragma unroll
    for (int rt = 0; rt < 2; ++rt)
#pragma unroll
    for (int r = 0; r < 4; ++r) {
        float v = bestv[rt][r];
        int   idx = besti[rt][r];
#pragma unroll
        for (int m = 8; m >= 1; m >>= 1) {
            float ov = __shfl_xor(v, m, 64);
            int   oi = __shfl_xor(idx, m, 64);
            if (ov < v || (ov == v && oi < idx)) { v = ov; idx = oi; }
        }
        if (col == 0) {
            int q = qbase + wid * 32 + rt * 16 + qd * 4 + r;
            u64 p = (((u64)fenc(v)) << 32) | (unsigned)idx;
            atomicMin(&pack[q], p);  // device-scope; ties -> smaller idx
        }
    }
}

// ---------------- Kernel C: epilogue (512 blocks x 256) ----------------
__global__ __launch_bounds__(256, 4)
void vq_post(const float* __restrict__ z_e, const float* __restrict__ emb,
             char* __restrict__ ws, float* __restrict__ out) {
    __shared__ int   fIdx[128];
    __shared__ float wsum[4];
    __shared__ int   amLast;

    int*   flags   = (int*)(ws + WS_FLAGS);
    float* ws_loss = (float*)(ws + WS_LOSS);
    int*   ws_cnt  = (int*)(ws + WS_CNT);
    const u64* pack = (const u64*)(ws + WS_PACK);

    const int tid  = threadIdx.x;
    const int lane = tid & 63;
    const int wid  = tid >> 6;
    const int qbase = blockIdx.x * 128;

    if (tid < 128) {
        u64 p = pack[qbase + tid];
        int idx = (int)(p & 0xFFFFFFFFu);
        fIdx[tid] = idx;
        out[TOT + 1 + qbase + tid] = (float)idx;
        atomicExch(&flags[idx], 1);  // device-scope
    }
    __syncthreads();

    const int q  = tid & 127;
    const int dh = tid >> 7;
    const int n  = qbase + q;
    const int bb = n >> 10;
    const int hw = n & (HW - 1);
    const int myIdx = fIdx[q];
    const float* erow = emb + myIdx * DIMS;
    float lsum = 0.f;
#pragma unroll
    for (int it = 0; it < 32; ++it) {
        int d = it * 2 + dh;
        float v = erow[d];
        int   o = bb * (DIMS * HW) + d * HW + hw;
        float ze = z_e[o];
        out[o] = v;
        float df = ze - v;
        lsum = fmaf(df, df, lsum);
    }
#pragma unroll
    for (int off = 32; off > 0; off >>= 1) lsum += __shfl_down(lsum, off, 64);
    if (lane == 0) wsum[wid] = lsum;
    __syncthreads();
    if (tid == 0) {
        atomicAdd(ws_loss, wsum[0] + wsum[1] + wsum[2] + wsum[3]);
        __threadfence();
        int prev = atomicAdd(ws_cnt, 1);
        amLast = (prev == (int)gridDim.x - 1);
    }
    __syncthreads();

    if (amLast) {
        __threadfence();
        float c = 0.f;
#pragma unroll
        for (int i = 0; i < 4; ++i)
            c += (float)atomicAdd(&flags[tid + 256 * i], 0);
#pragma unroll
        for (int off = 32; off > 0; off >>= 1) c += __shfl_down(c, off, 64);
        if (lane == 0) wsum[wid] = c;
        __syncthreads();
        if (tid == 0) {
            float used = wsum[0] + wsum[1] + wsum[2] + wsum[3];
            out[TOT + 1 + NQ] = used / (float)K_CODES;
            float L = atomicAdd(ws_loss, 0.f);
            out[TOT] = L / (float)TOT;
        }
    }
}

extern "C" void kernel_launch(void* const* d_in, const int* in_sizes, int n_in,
                              void* d_out, int out_size, void* d_ws, size_t ws_size,
                              hipStream_t stream) {
    const float* z_e = (const float*)d_in[0];
    const float* emb = (const float*)d_in[1];
    float* out = (float*)d_out;
    char* ws = (char*)d_ws;

    vq_prep<<<64, 256, 0, stream>>>(emb, ws);
    vq_main<<<1024, 256, 0, stream>>>(z_e, ws);
    vq_post<<<512, 256, 0, stream>>>(z_e, emb, ws, out);
}